// Round 4
// baseline (356.843 us; speedup 1.0000x reference)
//
#include <hip/hip_runtime.h>
#include <math.h>

#define Nn 8192
#define Dd 256
#define Kk 32

// ws float layout:
// [0,        4194304)  P[k][gh][blk][d]   32*2*256*256  (16 MB partials, no atomics)
// [4194304,  4325376)  P2[k][gh][c][d]    32*2*8*256    (512 KB, level-2 partials)
// [4325376,  4333568)  Sp[k][blk]         32*256        (per-block gamma sums, k-major)
// [4333568,  4334080)  flags[512]         (grid-barrier tokens, poison-immune)
#define P_OFF   0
#define P2_OFF  4194304
#define SP_OFF  4325376
#define FL_OFF  4333568

#define TOKA 0x1234ABCDu
#define TOKB 0x9876FEDCu

// Device-scope grid barrier: each block publishes a token in its own slot;
// threads 0..255 each spin on one slot. Release/acquire at agent scope +
// __threadfence makes phase-1/2 stores visible across XCDs.
__device__ __forceinline__ void grid_barrier(unsigned* fl, unsigned tok) {
    __syncthreads();
    __threadfence();
    if (threadIdx.x == 0)
        __hip_atomic_store(&fl[blockIdx.x], tok, __ATOMIC_RELEASE, __HIP_MEMORY_SCOPE_AGENT);
    if (threadIdx.x < 256) {
        while (__hip_atomic_load(&fl[threadIdx.x], __ATOMIC_ACQUIRE,
                                 __HIP_MEMORY_SCOPE_AGENT) != tok) {
            __builtin_amdgcn_s_sleep(2);
        }
    }
    __threadfence();
    __syncthreads();
}

// Single fused kernel: 256 blocks x 1024 thr (1 block/CU, all co-resident).
// Phase 1 = gamma + partial G/H (identical to the best-measured r2 body).
// Phase 2 = level-1 reduction of P (512 tiles, 2 per block).
// Phase 3 = final sums + S + epilogue (blocks 0..31).
__global__ __launch_bounds__(1024) void fused_all(const float* __restrict__ x,
                                                  const float* __restrict__ w,
                                                  const float* __restrict__ b,
                                                  float* __restrict__ ws,
                                                  float* __restrict__ out) {
    __shared__ __align__(16) float4 uS4[64 * 33];   // ~33.8 KB transposed pad+1
    __shared__ __align__(16) float4 vS4[64 * 33];   // ~33.8 KB
    __shared__ __align__(16) float4 xS4[32 * 64];   // 32 KB linear (DMA dest)
    __shared__ float  gS[1024];                     // gamma [r][k]; reused in phase 2
    __shared__ float  svS;

    float* P  = ws + P_OFF;
    float* P2 = ws + P2_OFF;
    float* Sp = ws + SP_OFF;
    unsigned* fl = (unsigned*)(ws + FL_OFF);
    int tid = threadIdx.x;
    int blk = blockIdx.x;

    // ---- insurance: clear stale tokens (runs ~15 us before anyone can arrive) ----
    if (blk == 0 && tid < 512)
        __hip_atomic_store(&fl[tid], 0u, __ATOMIC_RELAXED, __HIP_MEMORY_SCOPE_AGENT);

    // ================= phase 1: gamma + partial G/H =================
    // ---- async DMA: x tile -> LDS (completes at the barrier) ----
    {
        const float* xg = x + (size_t)blk * 32 * Dd;
        #pragma unroll
        for (int i = 0; i < 2; ++i) {
            int e4 = tid + i * 1024;
            __builtin_amdgcn_global_load_lds(
                (const __attribute__((address_space(1))) void*)(xg + (size_t)e4 * 4),
                (__attribute__((address_space(3))) void*)(&xS4[e4]),
                16, 0, 0);
        }
    }

    // ---- stage + transpose w, w*b into LDS (overlaps the x DMA) ----
    {
        const float4* w4 = (const float4*)w;
        const float4* b4 = (const float4*)b;
        #pragma unroll
        for (int i = 0; i < 2; ++i) {
            int e4 = tid + i * 1024;
            int k  = e4 >> 6;
            int d4 = e4 & 63;
            float4 wv = w4[e4];
            float4 bv = b4[e4];
            float4 vv = {wv.x * bv.x, wv.y * bv.y, wv.z * bv.z, wv.w * bv.w};
            uS4[d4 * 33 + k] = wv;
            vS4[d4 * 33 + k] = vv;
        }
    }
    __syncthreads();                          // drains vmcnt -> x DMA done too

    // ---- gamma: 16 waves x 2 rows; u,v,x all from LDS ----
    {
        int lane = tid & 63;
        int wave = tid >> 6;
        int k = lane & 31;
        int h = lane >> 5;
        int r0 = wave * 2;

        const float4* xr0 = &xS4[(r0 + 0) * 64];
        const float4* xr1 = &xS4[(r0 + 1) * 64];

        float4 a0 = {0.f, 0.f, 0.f, 0.f}, a1 = a0;

        #pragma unroll 8
        for (int i = 0; i < 32; ++i) {
            int ii = h * 32 + i;
            float4 u  = uS4[ii * 33 + k];
            float4 v  = vS4[ii * 33 + k];
            float4 x0 = xr0[ii];             // LDS broadcast within half-wave
            float4 x1 = xr1[ii];
            float y;
            y = fmaf(u.x, x0.x, v.x); a0.x = fmaf(y, y, a0.x);
            y = fmaf(u.y, x0.y, v.y); a0.y = fmaf(y, y, a0.y);
            y = fmaf(u.z, x0.z, v.z); a0.z = fmaf(y, y, a0.z);
            y = fmaf(u.w, x0.w, v.w); a0.w = fmaf(y, y, a0.w);
            y = fmaf(u.x, x1.x, v.x); a1.x = fmaf(y, y, a1.x);
            y = fmaf(u.y, x1.y, v.y); a1.y = fmaf(y, y, a1.y);
            y = fmaf(u.z, x1.z, v.z); a1.z = fmaf(y, y, a1.z);
            y = fmaf(u.w, x1.w, v.w); a1.w = fmaf(y, y, a1.w);
        }

        float s0 = (a0.x + a0.y) + (a0.z + a0.w);
        float s1 = (a1.x + a1.y) + (a1.z + a1.w);
        s0 += __shfl_xor(s0, 32);            // combine the two d-halves
        s1 += __shfl_xor(s1, 32);
        float y40 = -0.5f * s0, y41 = -0.5f * s1;

        float m0 = y40, m1 = y41;
        #pragma unroll
        for (int o = 16; o >= 1; o >>= 1) {
            m0 = fmaxf(m0, __shfl_xor(m0, o));
            m1 = fmaxf(m1, __shfl_xor(m1, o));
        }
        float e0 = __expf(y40 - m0), e1 = __expf(y41 - m1);
        float t0 = e0, t1 = e1;
        #pragma unroll
        for (int o = 16; o >= 1; o >>= 1) {
            t0 += __shfl_xor(t0, o);
            t1 += __shfl_xor(t1, o);
        }
        if (h == 0) {
            gS[(r0 + 0) * 32 + k] = e0 / t0;
            gS[(r0 + 1) * 32 + k] = e1 / t1;
        }
    }
    __syncthreads();

    // ---- per-block gamma sums -> Sp[k][blk] ----
    if (tid < 32) {
        float s0 = 0.f, s1 = 0.f, s2 = 0.f, s3 = 0.f;
        #pragma unroll
        for (int r = 0; r < 32; r += 4) {
            s0 += gS[(r + 0) * 32 + tid];
            s1 += gS[(r + 1) * 32 + tid];
            s2 += gS[(r + 2) * 32 + tid];
            s3 += gS[(r + 3) * 32 + tid];
        }
        Sp[tid * 256 + blk] = (s0 + s1) + (s2 + s3);
    }

    // ---- accumulate: thread = (kq, d); x and gamma both from LDS ----
    {
        int kq = tid >> 8;
        int d  = tid & 255;
        const float* xl = (const float*)xS4;
        const float4* gS4 = (const float4*)gS;

        float aG[8], aH[8];
        #pragma unroll
        for (int j = 0; j < 8; ++j) { aG[j] = 0.f; aH[j] = 0.f; }

        #pragma unroll 4
        for (int r = 0; r < 32; ++r) {
            float xv = xl[r * 256 + d];
            float xx = xv * xv;
            #pragma unroll
            for (int q = 0; q < 2; ++q) {
                float4 gv = gS4[r * 8 + kq * 2 + q];   // wave-uniform -> broadcast
                aG[4*q+0] = fmaf(gv.x, xv, aG[4*q+0]); aH[4*q+0] = fmaf(gv.x, xx, aH[4*q+0]);
                aG[4*q+1] = fmaf(gv.y, xv, aG[4*q+1]); aH[4*q+1] = fmaf(gv.y, xx, aH[4*q+1]);
                aG[4*q+2] = fmaf(gv.z, xv, aG[4*q+2]); aH[4*q+2] = fmaf(gv.z, xx, aH[4*q+2]);
                aG[4*q+3] = fmaf(gv.w, xv, aG[4*q+3]); aH[4*q+3] = fmaf(gv.w, xx, aH[4*q+3]);
            }
        }

        #pragma unroll
        for (int j = 0; j < 8; ++j) {
            int k = kq * 8 + j;
            P[((size_t)(k * 2 + 0) * 256 + blk) * 256 + d] = aG[j];
            P[((size_t)(k * 2 + 1) * 256 + blk) * 256 + d] = aH[j];
        }
    }

    // ================= barrier A =================
    grid_barrier(fl, TOKA);

    // ================= phase 2: reduce P (512 tiles, 2 per block) =================
    {
        int tt   = tid >> 9;                 // 0..1 -> tile within block
        int tile = blk * 2 + tt;             // == (k*2+gh)*8 + c
        int sub  = (tid >> 8) & 1;           // slab half (16 slabs each)
        int d    = tid & 255;

        const float* p = P + ((size_t)(tile >> 3) * 256 + (tile & 7) * 32 + sub * 16) * 256 + d;
        float s0 = 0.f, s1 = 0.f, s2 = 0.f, s3 = 0.f;
        #pragma unroll
        for (int i = 0; i < 16; i += 4) {
            s0 += p[(size_t)(i + 0) * 256];
            s1 += p[(size_t)(i + 1) * 256];
            s2 += p[(size_t)(i + 2) * 256];
            s3 += p[(size_t)(i + 3) * 256];
        }
        gS[tid] = (s0 + s1) + (s2 + s3);     // gS[tt][sub][d], layout matches tid
        __syncthreads();
        if (sub == 0)
            P2[(size_t)tile * 256 + d] = gS[tt * 512 + d] + gS[tt * 512 + 256 + d];
    }

    // ================= barrier B =================
    grid_barrier(fl, TOKB);

    // ================= phase 3: final sums + S + epilogue (blocks 0..31) =========
    if (blk < 32) {
        int k = blk;
        if (tid < 64) {
            float sv_part = Sp[k * 256 + tid]       + Sp[k * 256 + 64 + tid]
                          + Sp[k * 256 + 128 + tid] + Sp[k * 256 + 192 + tid];
            #pragma unroll
            for (int o = 32; o >= 1; o >>= 1) sv_part += __shfl_xor(sv_part, o);
            if (tid == 0) svS = sv_part;
        }
        __syncthreads();
        if (tid < 256) {
            int d = tid;
            float sv = svS;
            const float* pg = P2 + (size_t)(k * 2 + 0) * 8 * 256 + d;
            const float* ph = P2 + (size_t)(k * 2 + 1) * 8 * 256 + d;
            float Gv = 0.f, Hv = 0.f;
            #pragma unroll
            for (int c = 0; c < 8; ++c) {
                Gv += pg[c * 256];
                Hv += ph[c * 256];
            }

            int idx = k * Dd + d;
            float wv = w[idx], bv = b[idx];
            const float invN = 1.0f / 8192.0f;
            const float c2 = 0.70710678118654752440f * invN;   // 1/(sqrt(2)*N)
            float mu = wv * (Gv + bv * sv) * invN;
            float w2 = wv * wv;
            float sg = (w2 * (Hv + 2.0f * bv * Gv + bv * bv * sv) - sv) * c2;
            out[idx] = sg;              // sigma_part
            out[Kk * Dd + idx] = mu;    // mu_part
        }
    }
}

extern "C" void kernel_launch(void* const* d_in, const int* in_sizes, int n_in,
                              void* d_out, int out_size, void* d_ws, size_t ws_size,
                              hipStream_t stream) {
    const float* x = (const float*)d_in[0];
    const float* w = (const float*)d_in[1];
    const float* b = (const float*)d_in[2];
    float* out = (float*)d_out;
    float* ws = (float*)d_ws;

    hipLaunchKernelGGL(fused_all, dim3(256), dim3(1024), 0, stream, x, w, b, ws, out);
}

// Round 6
// 152.396 us; speedup vs baseline: 2.3415x; 2.3415x over previous
//
#include <hip/hip_runtime.h>
#include <math.h>

#define Nn 8192
#define Dd 256
#define Kk 32

// ws float layout:
// [0,        4194304)  P[k][gh][blk][d]   32*2*256*256  (16 MB partials, no atomics)
// [4194304,  4325376)  P2[k][gh][c][d]    32*2*8*256    (512 KB, level-2 partials)
// [4325376,  4333568)  Sp[k][blk]         32*256        (per-block gamma sums, k-major)
// [4333568,  4333569)  counter            (last-done ticket counter; K1 resets it)
#define P_OFF   0
#define P2_OFF  4194304
#define SP_OFF  4325376
#define FL_OFF  4333568

// ---- gamma-phase probe: staging + gamma + softmax + Sp ONLY (idempotent). ----
// Launched 4x before the real pipeline purely to measure the gamma-side phase
// duration: dur_delta = 4 * (T_gammaside + gap). Writes the same Sp values
// the real K1 rewrites afterwards -> correctness unaffected.
__global__ __launch_bounds__(1024) void gamma_probe(const float* __restrict__ x,
                                                    const float* __restrict__ w,
                                                    const float* __restrict__ b,
                                                    float* __restrict__ ws) {
    __shared__ __align__(16) float4 uS4[64 * 33];
    __shared__ __align__(16) float4 vS4[64 * 33];
    __shared__ __align__(16) float4 xS4[32 * 64];
    __shared__ float  gS[1024];

    float* Sp = ws + SP_OFF;
    int tid = threadIdx.x;
    int blk = blockIdx.x;

    {
        const float* xg = x + (size_t)blk * 32 * Dd;
        #pragma unroll
        for (int i = 0; i < 2; ++i) {
            int e4 = tid + i * 1024;
            __builtin_amdgcn_global_load_lds(
                (const __attribute__((address_space(1))) void*)(xg + (size_t)e4 * 4),
                (__attribute__((address_space(3))) void*)(&xS4[e4]),
                16, 0, 0);
        }
    }
    {
        const float4* w4 = (const float4*)w;
        const float4* b4 = (const float4*)b;
        #pragma unroll
        for (int i = 0; i < 2; ++i) {
            int e4 = tid + i * 1024;
            int k  = e4 >> 6;
            int d4 = e4 & 63;
            float4 wv = w4[e4];
            float4 bv = b4[e4];
            float4 vv = {wv.x * bv.x, wv.y * bv.y, wv.z * bv.z, wv.w * bv.w};
            uS4[d4 * 33 + k] = wv;
            vS4[d4 * 33 + k] = vv;
        }
    }
    __syncthreads();

    {
        int lane = tid & 63;
        int wave = tid >> 6;
        int k = lane & 31;
        int h = lane >> 5;
        int r0 = wave * 2;

        const float4* xr0 = &xS4[(r0 + 0) * 64];
        const float4* xr1 = &xS4[(r0 + 1) * 64];

        float4 a0 = {0.f, 0.f, 0.f, 0.f}, a1 = a0;

        #pragma unroll 8
        for (int i = 0; i < 32; ++i) {
            int ii = h * 32 + i;
            float4 u  = uS4[ii * 33 + k];
            float4 v  = vS4[ii * 33 + k];
            float4 x0 = xr0[ii];
            float4 x1 = xr1[ii];
            float y;
            y = fmaf(u.x, x0.x, v.x); a0.x = fmaf(y, y, a0.x);
            y = fmaf(u.y, x0.y, v.y); a0.y = fmaf(y, y, a0.y);
            y = fmaf(u.z, x0.z, v.z); a0.z = fmaf(y, y, a0.z);
            y = fmaf(u.w, x0.w, v.w); a0.w = fmaf(y, y, a0.w);
            y = fmaf(u.x, x1.x, v.x); a1.x = fmaf(y, y, a1.x);
            y = fmaf(u.y, x1.y, v.y); a1.y = fmaf(y, y, a1.y);
            y = fmaf(u.z, x1.z, v.z); a1.z = fmaf(y, y, a1.z);
            y = fmaf(u.w, x1.w, v.w); a1.w = fmaf(y, y, a1.w);
        }

        float s0 = (a0.x + a0.y) + (a0.z + a0.w);
        float s1 = (a1.x + a1.y) + (a1.z + a1.w);
        s0 += __shfl_xor(s0, 32);
        s1 += __shfl_xor(s1, 32);
        float y40 = -0.5f * s0, y41 = -0.5f * s1;

        float m0 = y40, m1 = y41;
        #pragma unroll
        for (int o = 16; o >= 1; o >>= 1) {
            m0 = fmaxf(m0, __shfl_xor(m0, o));
            m1 = fmaxf(m1, __shfl_xor(m1, o));
        }
        float e0 = __expf(y40 - m0), e1 = __expf(y41 - m1);
        float t0 = e0, t1 = e1;
        #pragma unroll
        for (int o = 16; o >= 1; o >>= 1) {
            t0 += __shfl_xor(t0, o);
            t1 += __shfl_xor(t1, o);
        }
        if (h == 0) {
            gS[(r0 + 0) * 32 + k] = e0 / t0;
            gS[(r0 + 1) * 32 + k] = e1 / t1;
        }
    }
    __syncthreads();

    if (tid < 32) {
        float s0 = 0.f, s1 = 0.f, s2 = 0.f, s3 = 0.f;
        #pragma unroll
        for (int r = 0; r < 32; r += 4) {
            s0 += gS[(r + 0) * 32 + tid];
            s1 += gS[(r + 1) * 32 + tid];
            s2 += gS[(r + 2) * 32 + tid];
            s3 += gS[(r + 3) * 32 + tid];
        }
        Sp[tid * 256 + blk] = (s0 + s1) + (s2 + s3);
    }
}

// K1: fused gamma + partial G/H (identical to the best-measured r2 kernel,
// plus a 1-word counter reset for the merged reduction kernel).
__global__ __launch_bounds__(1024) void fused_kernel(const float* __restrict__ x,
                                                     const float* __restrict__ w,
                                                     const float* __restrict__ b,
                                                     float* __restrict__ ws) {
    __shared__ __align__(16) float4 uS4[64 * 33];   // ~33.8 KB transposed pad+1
    __shared__ __align__(16) float4 vS4[64 * 33];   // ~33.8 KB
    __shared__ __align__(16) float4 xS4[32 * 64];   // 32 KB linear (DMA dest)
    __shared__ float  gS[1024];                     // gamma [r][k] 4 KB

    float* P  = ws + P_OFF;
    float* Sp = ws + SP_OFF;
    int tid = threadIdx.x;
    int blk = blockIdx.x;

    // reset the last-done counter (poison-proof: runs before red12 every iter)
    if (blk == 0 && tid == 0)
        __hip_atomic_store((unsigned*)(ws + FL_OFF), 0u,
                           __ATOMIC_RELAXED, __HIP_MEMORY_SCOPE_AGENT);

    {
        const float* xg = x + (size_t)blk * 32 * Dd;
        #pragma unroll
        for (int i = 0; i < 2; ++i) {
            int e4 = tid + i * 1024;
            __builtin_amdgcn_global_load_lds(
                (const __attribute__((address_space(1))) void*)(xg + (size_t)e4 * 4),
                (__attribute__((address_space(3))) void*)(&xS4[e4]),
                16, 0, 0);
        }
    }
    {
        const float4* w4 = (const float4*)w;
        const float4* b4 = (const float4*)b;
        #pragma unroll
        for (int i = 0; i < 2; ++i) {
            int e4 = tid + i * 1024;
            int k  = e4 >> 6;
            int d4 = e4 & 63;
            float4 wv = w4[e4];
            float4 bv = b4[e4];
            float4 vv = {wv.x * bv.x, wv.y * bv.y, wv.z * bv.z, wv.w * bv.w};
            uS4[d4 * 33 + k] = wv;
            vS4[d4 * 33 + k] = vv;
        }
    }
    __syncthreads();                          // drains vmcnt -> x DMA done too

    {
        int lane = tid & 63;
        int wave = tid >> 6;
        int k = lane & 31;
        int h = lane >> 5;
        int r0 = wave * 2;

        const float4* xr0 = &xS4[(r0 + 0) * 64];
        const float4* xr1 = &xS4[(r0 + 1) * 64];

        float4 a0 = {0.f, 0.f, 0.f, 0.f}, a1 = a0;

        #pragma unroll 8
        for (int i = 0; i < 32; ++i) {
            int ii = h * 32 + i;
            float4 u  = uS4[ii * 33 + k];
            float4 v  = vS4[ii * 33 + k];
            float4 x0 = xr0[ii];             // LDS broadcast within half-wave
            float4 x1 = xr1[ii];
            float y;
            y = fmaf(u.x, x0.x, v.x); a0.x = fmaf(y, y, a0.x);
            y = fmaf(u.y, x0.y, v.y); a0.y = fmaf(y, y, a0.y);
            y = fmaf(u.z, x0.z, v.z); a0.z = fmaf(y, y, a0.z);
            y = fmaf(u.w, x0.w, v.w); a0.w = fmaf(y, y, a0.w);
            y = fmaf(u.x, x1.x, v.x); a1.x = fmaf(y, y, a1.x);
            y = fmaf(u.y, x1.y, v.y); a1.y = fmaf(y, y, a1.y);
            y = fmaf(u.z, x1.z, v.z); a1.z = fmaf(y, y, a1.z);
            y = fmaf(u.w, x1.w, v.w); a1.w = fmaf(y, y, a1.w);
        }

        float s0 = (a0.x + a0.y) + (a0.z + a0.w);
        float s1 = (a1.x + a1.y) + (a1.z + a1.w);
        s0 += __shfl_xor(s0, 32);            // combine the two d-halves
        s1 += __shfl_xor(s1, 32);
        float y40 = -0.5f * s0, y41 = -0.5f * s1;

        float m0 = y40, m1 = y41;
        #pragma unroll
        for (int o = 16; o >= 1; o >>= 1) {
            m0 = fmaxf(m0, __shfl_xor(m0, o));
            m1 = fmaxf(m1, __shfl_xor(m1, o));
        }
        float e0 = __expf(y40 - m0), e1 = __expf(y41 - m1);
        float t0 = e0, t1 = e1;
        #pragma unroll
        for (int o = 16; o >= 1; o >>= 1) {
            t0 += __shfl_xor(t0, o);
            t1 += __shfl_xor(t1, o);
        }
        if (h == 0) {
            gS[(r0 + 0) * 32 + k] = e0 / t0;
            gS[(r0 + 1) * 32 + k] = e1 / t1;
        }
    }
    __syncthreads();

    if (tid < 32) {
        float s0 = 0.f, s1 = 0.f, s2 = 0.f, s3 = 0.f;
        #pragma unroll
        for (int r = 0; r < 32; r += 4) {
            s0 += gS[(r + 0) * 32 + tid];
            s1 += gS[(r + 1) * 32 + tid];
            s2 += gS[(r + 2) * 32 + tid];
            s3 += gS[(r + 3) * 32 + tid];
        }
        Sp[tid * 256 + blk] = (s0 + s1) + (s2 + s3);
    }

    {
        int kq = tid >> 8;
        int d  = tid & 255;
        const float* xl = (const float*)xS4;
        const float4* gS4 = (const float4*)gS;

        float aG[8], aH[8];
        #pragma unroll
        for (int j = 0; j < 8; ++j) { aG[j] = 0.f; aH[j] = 0.f; }

        #pragma unroll 4
        for (int r = 0; r < 32; ++r) {
            float xv = xl[r * 256 + d];
            float xx = xv * xv;
            #pragma unroll
            for (int q = 0; q < 2; ++q) {
                float4 gv = gS4[r * 8 + kq * 2 + q];   // wave-uniform -> broadcast
                aG[4*q+0] = fmaf(gv.x, xv, aG[4*q+0]); aH[4*q+0] = fmaf(gv.x, xx, aH[4*q+0]);
                aG[4*q+1] = fmaf(gv.y, xv, aG[4*q+1]); aH[4*q+1] = fmaf(gv.y, xx, aH[4*q+1]);
                aG[4*q+2] = fmaf(gv.z, xv, aG[4*q+2]); aH[4*q+2] = fmaf(gv.z, xx, aH[4*q+2]);
                aG[4*q+3] = fmaf(gv.w, xv, aG[4*q+3]); aH[4*q+3] = fmaf(gv.w, xx, aH[4*q+3]);
            }
        }

        #pragma unroll
        for (int j = 0; j < 8; ++j) {
            int k = kq * 8 + j;
            P[((size_t)(k * 2 + 0) * 256 + blk) * 256 + d] = aG[j];
            P[((size_t)(k * 2 + 1) * 256 + blk) * 256 + d] = aH[j];
        }
    }
}

// K2+K3 merged: 512 blocks x 256 thr. Each block reduces one P tile -> P2,
// takes a ticket; the last 32 blocks (tickets 480..511) each run the per-k
// epilogue after the counter hits 512 (all P2 writes fenced-before-increment).
__global__ __launch_bounds__(256) void red12_kernel(const float* __restrict__ w,
                                                    const float* __restrict__ b,
                                                    float* __restrict__ ws,
                                                    float* __restrict__ out) {
    const float* P = ws + P_OFF;
    float* P2 = ws + P2_OFF;
    const float* Sp = ws + SP_OFF;
    unsigned* counter = (unsigned*)(ws + FL_OFF);
    __shared__ unsigned tktS;
    __shared__ float sred[4];
    int tid = threadIdx.x;

    // ---- level-1 reduction (identical to old K2) ----
    {
        int k  = blockIdx.x >> 4;
        int gh = (blockIdx.x >> 3) & 1;
        int c  = blockIdx.x & 7;

        const float* p = P + ((size_t)(k * 2 + gh) * 256 + c * 32) * 256 + tid;
        float s0 = 0.f, s1 = 0.f, s2 = 0.f, s3 = 0.f;
        #pragma unroll
        for (int i = 0; i < 32; i += 4) {
            s0 += p[(size_t)(i + 0) * 256];
            s1 += p[(size_t)(i + 1) * 256];
            s2 += p[(size_t)(i + 2) * 256];
            s3 += p[(size_t)(i + 3) * 256];
        }
        P2[((size_t)(k * 2 + gh) * 8 + c) * 256 + tid] = (s0 + s1) + (s2 + s3);
    }

    // ---- last-done election ----
    __threadfence();                          // P2 store visible before increment
    if (tid == 0) tktS = atomicAdd(counter, 1u);
    __syncthreads();
    unsigned tkt = tktS;
    if (tkt < 480u) return;                   // uniform per block

    int k = (int)tkt - 480;                   // unique k in [0,32)
    if (tid == 0) {
        while (__hip_atomic_load(counter, __ATOMIC_ACQUIRE,
                                 __HIP_MEMORY_SCOPE_AGENT) != 512u) {
            __builtin_amdgcn_s_sleep(2);
        }
    }
    __syncthreads();
    __threadfence();

    // ---- per-k epilogue (identical to old K3) ----
    {
        int d = tid;
        float sv_part = Sp[k * 256 + d];
        #pragma unroll
        for (int o = 32; o >= 1; o >>= 1) sv_part += __shfl_xor(sv_part, o);
        if ((d & 63) == 0) sred[d >> 6] = sv_part;
        __syncthreads();
        float sv = (sred[0] + sred[1]) + (sred[2] + sred[3]);

        const float* pg = P2 + (size_t)(k * 2 + 0) * 8 * 256 + d;
        const float* ph = P2 + (size_t)(k * 2 + 1) * 8 * 256 + d;
        float Gv = 0.f, Hv = 0.f;
        #pragma unroll
        for (int c = 0; c < 8; ++c) {
            Gv += pg[c * 256];
            Hv += ph[c * 256];
        }

        int idx = k * Dd + d;
        float wv = w[idx], bv = b[idx];
        const float invN = 1.0f / 8192.0f;
        const float c2 = 0.70710678118654752440f * invN;   // 1/(sqrt(2)*N)
        float mu = wv * (Gv + bv * sv) * invN;
        float w2 = wv * wv;
        float sg = (w2 * (Hv + 2.0f * bv * Gv + bv * bv * sv) - sv) * c2;
        out[idx] = sg;              // sigma_part
        out[Kk * Dd + idx] = mu;    // mu_part
    }
}

extern "C" void kernel_launch(void* const* d_in, const int* in_sizes, int n_in,
                              void* d_out, int out_size, void* d_ws, size_t ws_size,
                              hipStream_t stream) {
    const float* x = (const float*)d_in[0];
    const float* w = (const float*)d_in[1];
    const float* b = (const float*)d_in[2];
    float* out = (float*)d_out;
    float* ws = (float*)d_ws;

    // 4 idempotent gamma-side probes (diagnosis: dur delta = 4*(T_gammaside + gap))
    hipLaunchKernelGGL(gamma_probe, dim3(256), dim3(1024), 0, stream, x, w, b, ws);
    hipLaunchKernelGGL(gamma_probe, dim3(256), dim3(1024), 0, stream, x, w, b, ws);
    hipLaunchKernelGGL(gamma_probe, dim3(256), dim3(1024), 0, stream, x, w, b, ws);
    hipLaunchKernelGGL(gamma_probe, dim3(256), dim3(1024), 0, stream, x, w, b, ws);

    hipLaunchKernelGGL(fused_kernel, dim3(256), dim3(1024), 0, stream, x, w, b, ws);
    hipLaunchKernelGGL(red12_kernel, dim3(512), dim3(256),  0, stream, w, b, ws, out);
}

// Round 8
// 79.820 us; speedup vs baseline: 4.4706x; 1.9092x over previous
//
#include <hip/hip_runtime.h>
#include <math.h>

#define Nn 8192
#define Dd 256
#define Kk 32

typedef float f4x __attribute__((ext_vector_type(4)));   // native vec for nt builtins

// ws float layout:
// [0,        4194304)  P[k][gh][blk][d]   32*2*256*256  (16 MB partials, no atomics)
// [4194304,  4325376)  P2[k][gh][c][d]    32*2*8*256    (512 KB, level-2 partials)
// [4325376,  4333568)  Sp[k][blk]         32*256        (per-block gamma sums, k-major)
#define P_OFF   0
#define P2_OFF  4194304
#define SP_OFF  4325376

// K1: fused gamma + partial G/H (identical to the best-measured r2 kernel,
// except P partials are written with NONTEMPORAL stores: P is produce-once/
// consume-once by another kernel, so streaming past L2 lets K2 read clean
// lines from L3/HBM instead of probing dirty remote-XCD L2 lines).
__global__ __launch_bounds__(1024) void fused_kernel(const float* __restrict__ x,
                                                     const float* __restrict__ w,
                                                     const float* __restrict__ b,
                                                     float* __restrict__ ws) {
    __shared__ __align__(16) float4 uS4[64 * 33];   // ~33.8 KB transposed pad+1
    __shared__ __align__(16) float4 vS4[64 * 33];   // ~33.8 KB
    __shared__ __align__(16) float4 xS4[32 * 64];   // 32 KB linear (DMA dest)
    __shared__ float  gS[1024];                     // gamma [r][k] 4 KB

    float* P  = ws + P_OFF;
    float* Sp = ws + SP_OFF;
    int tid = threadIdx.x;
    int blk = blockIdx.x;

    // ---- async DMA: x tile -> LDS (completes at the barrier) ----
    {
        const float* xg = x + (size_t)blk * 32 * Dd;
        #pragma unroll
        for (int i = 0; i < 2; ++i) {
            int e4 = tid + i * 1024;
            __builtin_amdgcn_global_load_lds(
                (const __attribute__((address_space(1))) void*)(xg + (size_t)e4 * 4),
                (__attribute__((address_space(3))) void*)(&xS4[e4]),
                16, 0, 0);
        }
    }

    // ---- stage + transpose w, w*b into LDS (overlaps the x DMA) ----
    {
        const float4* w4 = (const float4*)w;
        const float4* b4 = (const float4*)b;
        #pragma unroll
        for (int i = 0; i < 2; ++i) {
            int e4 = tid + i * 1024;
            int k  = e4 >> 6;
            int d4 = e4 & 63;
            float4 wv = w4[e4];
            float4 bv = b4[e4];
            float4 vv = {wv.x * bv.x, wv.y * bv.y, wv.z * bv.z, wv.w * bv.w};
            uS4[d4 * 33 + k] = wv;
            vS4[d4 * 33 + k] = vv;
        }
    }
    __syncthreads();                          // drains vmcnt -> x DMA done too

    // ---- gamma: 16 waves x 2 rows; u,v,x all from LDS ----
    {
        int lane = tid & 63;
        int wave = tid >> 6;
        int k = lane & 31;
        int h = lane >> 5;
        int r0 = wave * 2;

        const float4* xr0 = &xS4[(r0 + 0) * 64];
        const float4* xr1 = &xS4[(r0 + 1) * 64];

        float4 a0 = {0.f, 0.f, 0.f, 0.f}, a1 = a0;

        #pragma unroll 8
        for (int i = 0; i < 32; ++i) {
            int ii = h * 32 + i;
            float4 u  = uS4[ii * 33 + k];
            float4 v  = vS4[ii * 33 + k];
            float4 x0 = xr0[ii];             // LDS broadcast within half-wave
            float4 x1 = xr1[ii];
            float y;
            y = fmaf(u.x, x0.x, v.x); a0.x = fmaf(y, y, a0.x);
            y = fmaf(u.y, x0.y, v.y); a0.y = fmaf(y, y, a0.y);
            y = fmaf(u.z, x0.z, v.z); a0.z = fmaf(y, y, a0.z);
            y = fmaf(u.w, x0.w, v.w); a0.w = fmaf(y, y, a0.w);
            y = fmaf(u.x, x1.x, v.x); a1.x = fmaf(y, y, a1.x);
            y = fmaf(u.y, x1.y, v.y); a1.y = fmaf(y, y, a1.y);
            y = fmaf(u.z, x1.z, v.z); a1.z = fmaf(y, y, a1.z);
            y = fmaf(u.w, x1.w, v.w); a1.w = fmaf(y, y, a1.w);
        }

        float s0 = (a0.x + a0.y) + (a0.z + a0.w);
        float s1 = (a1.x + a1.y) + (a1.z + a1.w);
        s0 += __shfl_xor(s0, 32);            // combine the two d-halves
        s1 += __shfl_xor(s1, 32);
        float y40 = -0.5f * s0, y41 = -0.5f * s1;

        float m0 = y40, m1 = y41;
        #pragma unroll
        for (int o = 16; o >= 1; o >>= 1) {
            m0 = fmaxf(m0, __shfl_xor(m0, o));
            m1 = fmaxf(m1, __shfl_xor(m1, o));
        }
        float e0 = __expf(y40 - m0), e1 = __expf(y41 - m1);
        float t0 = e0, t1 = e1;
        #pragma unroll
        for (int o = 16; o >= 1; o >>= 1) {
            t0 += __shfl_xor(t0, o);
            t1 += __shfl_xor(t1, o);
        }
        if (h == 0) {
            gS[(r0 + 0) * 32 + k] = e0 / t0;
            gS[(r0 + 1) * 32 + k] = e1 / t1;
        }
    }
    __syncthreads();

    // ---- per-block gamma sums -> Sp[k][blk] (k-major: K3 reads coalesced) ----
    if (tid < 32) {
        float s0 = 0.f, s1 = 0.f, s2 = 0.f, s3 = 0.f;
        #pragma unroll
        for (int r = 0; r < 32; r += 4) {
            s0 += gS[(r + 0) * 32 + tid];
            s1 += gS[(r + 1) * 32 + tid];
            s2 += gS[(r + 2) * 32 + tid];
            s3 += gS[(r + 3) * 32 + tid];
        }
        Sp[tid * 256 + blk] = (s0 + s1) + (s2 + s3);
    }

    // ---- accumulate: thread = (kq, d); x and gamma both from LDS ----
    {
        int kq = tid >> 8;                   // 0..3 -> k in [8*kq, 8*kq+8)
        int d  = tid & 255;
        const float* xl = (const float*)xS4; // [r*256 + d], conflict-free b32
        const float4* gS4 = (const float4*)gS;

        float aG[8], aH[8];
        #pragma unroll
        for (int j = 0; j < 8; ++j) { aG[j] = 0.f; aH[j] = 0.f; }

        #pragma unroll 4
        for (int r = 0; r < 32; ++r) {
            float xv = xl[r * 256 + d];
            float xx = xv * xv;
            #pragma unroll
            for (int q = 0; q < 2; ++q) {
                float4 gv = gS4[r * 8 + kq * 2 + q];   // wave-uniform -> broadcast
                aG[4*q+0] = fmaf(gv.x, xv, aG[4*q+0]); aH[4*q+0] = fmaf(gv.x, xx, aH[4*q+0]);
                aG[4*q+1] = fmaf(gv.y, xv, aG[4*q+1]); aH[4*q+1] = fmaf(gv.y, xx, aH[4*q+1]);
                aG[4*q+2] = fmaf(gv.z, xv, aG[4*q+2]); aH[4*q+2] = fmaf(gv.z, xx, aH[4*q+2]);
                aG[4*q+3] = fmaf(gv.w, xv, aG[4*q+3]); aH[4*q+3] = fmaf(gv.w, xx, aH[4*q+3]);
            }
        }

        #pragma unroll
        for (int j = 0; j < 8; ++j) {
            int k = kq * 8 + j;
            __builtin_nontemporal_store(aG[j], &P[((size_t)(k * 2 + 0) * 256 + blk) * 256 + d]);
            __builtin_nontemporal_store(aH[j], &P[((size_t)(k * 2 + 1) * 256 + blk) * 256 + d]);
        }
    }
}

// K2: 512 blocks x 256 thr; block = one 32-row chunk of the [16384][256] P view.
// f4x nontemporal loads (16 B/lane), 8 independent loads/thread, LDS combine.
__global__ __launch_bounds__(256) void red1_kernel(float* __restrict__ ws) {
    const f4x* P4  = (const f4x*)(ws + P_OFF);
    f4x*       P24 = (f4x*)(ws + P2_OFF);
    __shared__ __align__(16) f4x sS[256];
    int tid = threadIdx.x;
    int c4  = tid & 63;                      // col4 0..63 (256 cols as float4)
    int g   = tid >> 6;                      // rowgroup 0..3 (8 rows each)

    // tile t reduces P rows [t*32, t*32+32); row stride = 64 float4s
    const f4x* p = P4 + ((size_t)blockIdx.x * 32 + g * 8) * 64 + c4;
    f4x a0 = {0.f, 0.f, 0.f, 0.f}, a1 = a0;
    #pragma unroll
    for (int i = 0; i < 8; i += 2) {
        f4x v0 = __builtin_nontemporal_load(&p[(size_t)(i + 0) * 64]);
        f4x v1 = __builtin_nontemporal_load(&p[(size_t)(i + 1) * 64]);
        a0 += v0;
        a1 += v1;
    }
    sS[tid] = a0 + a1;
    __syncthreads();

    if (g == 0) {
        f4x out = (sS[c4] + sS[64 + c4]) + (sS[128 + c4] + sS[192 + c4]);
        P24[(size_t)blockIdx.x * 64 + c4] = out;
    }
}

// K3: 32 blocks x 256 thr; block=k, thread=d. Final sums + S + epilogue.
__global__ __launch_bounds__(256) void red2_kernel(const float* __restrict__ w,
                                                   const float* __restrict__ b,
                                                   const float* __restrict__ ws,
                                                   float* __restrict__ out) {
    const float* P2 = ws + P2_OFF;
    const float* Sp = ws + SP_OFF;
    __shared__ float sred[4];
    int k = blockIdx.x, d = threadIdx.x;

    // ---- S[k] = sum over 256 blocks (coalesced: Sp is k-major) ----
    float sv_part = Sp[k * 256 + d];
    #pragma unroll
    for (int o = 32; o >= 1; o >>= 1) sv_part += __shfl_xor(sv_part, o);
    if ((d & 63) == 0) sred[d >> 6] = sv_part;
    __syncthreads();
    float sv = (sred[0] + sred[1]) + (sred[2] + sred[3]);

    const float* pg = P2 + (size_t)(k * 2 + 0) * 8 * 256 + d;
    const float* ph = P2 + (size_t)(k * 2 + 1) * 8 * 256 + d;
    float Gv = 0.f, Hv = 0.f;
    #pragma unroll
    for (int c = 0; c < 8; ++c) {
        Gv += pg[c * 256];
        Hv += ph[c * 256];
    }

    int idx = k * Dd + d;
    float wv = w[idx], bv = b[idx];
    const float invN = 1.0f / 8192.0f;
    const float c2 = 0.70710678118654752440f * invN;   // 1/(sqrt(2)*N)
    float mu = wv * (Gv + bv * sv) * invN;
    float w2 = wv * wv;
    float sg = (w2 * (Hv + 2.0f * bv * Gv + bv * bv * sv) - sv) * c2;
    out[idx] = sg;              // sigma_part
    out[Kk * Dd + idx] = mu;    // mu_part
}

extern "C" void kernel_launch(void* const* d_in, const int* in_sizes, int n_in,
                              void* d_out, int out_size, void* d_ws, size_t ws_size,
                              hipStream_t stream) {
    const float* x = (const float*)d_in[0];
    const float* w = (const float*)d_in[1];
    const float* b = (const float*)d_in[2];
    float* out = (float*)d_out;
    float* ws = (float*)d_ws;

    hipLaunchKernelGGL(fused_kernel, dim3(256), dim3(1024), 0, stream, x, w, b, ws);
    hipLaunchKernelGGL(red1_kernel,  dim3(512), dim3(256),  0, stream, ws);
    hipLaunchKernelGGL(red2_kernel,  dim3(32),  dim3(256),  0, stream, w, b, ws, out);
}